// Round 2
// baseline (5905.971 us; speedup 1.0000x reference)
//
#include <hip/hip_runtime.h>

typedef unsigned short u16;
typedef short bf16x8 __attribute__((ext_vector_type(8)));
typedef float f32x4 __attribute__((ext_vector_type(4)));

// B=32, S=T=100, E=512, H=512, VT=32000. All float tensors are fp32 in
// global memory; bf16 only as MFMA operands (converted at staging time).
// gate order (PyTorch): i,f,g,o rows of [4H, *] weights.

__device__ __forceinline__ u16 f2bf(float f) {
    unsigned u = __builtin_bit_cast(unsigned, f);
    return (u16)((u + 0x7FFFu + ((u >> 16) & 1u)) >> 16);
}
__device__ __forceinline__ float sigm(float x) { return 1.0f / (1.0f + __expf(-x)); }
__device__ __forceinline__ float tanh_(float x) { return 2.0f / (1.0f + __expf(-2.0f * x)) - 1.0f; }
__device__ __forceinline__ f32x4 mfma16(bf16x8 a, bf16x8 b, f32x4 c) {
    return __builtin_amdgcn_mfma_f32_16x16x32_bf16(a, b, c, 0, 0, 0);
}
__device__ __forceinline__ uint4 pack8(float4 a, float4 b) {
    union { u16 h[8]; uint4 v; } u;
    u.h[0] = f2bf(a.x); u.h[1] = f2bf(a.y); u.h[2] = f2bf(a.z); u.h[3] = f2bf(a.w);
    u.h[4] = f2bf(b.x); u.h[5] = f2bf(b.y); u.h[6] = f2bf(b.z); u.h[7] = f2bf(b.w);
    return u.v;
}

// ---------------- weight conversion ----------------
__global__ __launch_bounds__(256) void convert_f2b(const float* __restrict__ src,
                                                   u16* __restrict__ dst, int n) {
    int i = (blockIdx.x * 256 + threadIdx.x) * 4;
    if (i < n) {
        float4 v = *(const float4*)(src + i);
        dst[i] = f2bf(v.x); dst[i + 1] = f2bf(v.y);
        dst[i + 2] = f2bf(v.z); dst[i + 3] = f2bf(v.w);
    }
}
// W2[n][k] = k<1024 ? dec_Wih[n][512+k] : dec_Whh[n][k-1024]   (n in [0,2048))
__global__ __launch_bounds__(256) void build_w2(const float* __restrict__ Wih,
                                                const float* __restrict__ Whh,
                                                u16* __restrict__ W2) {
    int n = blockIdx.x;
    for (int i = 0; i < 6; i++) {
        int k = i * 256 + threadIdx.x;
        float v = (k < 1024) ? Wih[(size_t)n * 1536 + 512 + k]
                             : Whh[(size_t)n * 512 + (k - 1024)];
        W2[(size_t)n * 1536 + k] = f2bf(v);
    }
}
// a1Wh[n][k] = att1_W[n][1024+k], bf16, n<1536, k<512
__global__ __launch_bounds__(256) void build_a1wh(const float* __restrict__ a1W,
                                                  u16* __restrict__ dst) {
    int n = blockIdx.x;
    for (int i = 0; i < 2; i++) {
        int k = i * 256 + threadIdx.x;
        dst[(size_t)n * 512 + k] = f2bf(a1W[(size_t)n * 1536 + 1024 + k]);
    }
}

// ---------------- embedding gathers (fp32) ----------------
// xs[s*32+b][0:512] = src_emb[source_data[b,s]]   (time-major)
__global__ __launch_bounds__(256) void embed_src(const int* __restrict__ tok,
                                                 const float* __restrict__ emb,
                                                 float* __restrict__ xs) {
    int g = blockIdx.x * 256 + threadIdx.x;      // 3200*64
    int row = g >> 6, c = (g & 63) * 8;
    int s = row >> 5, b = row & 31;
    int id = tok[b * 100 + s];
    *(float4*)(xs + (size_t)row * 512 + c) = *(const float4*)(emb + (size_t)id * 512 + c);
    *(float4*)(xs + (size_t)row * 512 + c + 4) = *(const float4*)(emb + (size_t)id * 512 + c + 4);
}
// clsin[(b*100+t)*2048 + 0:512] = tgt_emb[target_data[b,t]]
__global__ __launch_bounds__(256) void embed_tgt(const int* __restrict__ tok,
                                                 const float* __restrict__ emb,
                                                 float* __restrict__ cls_in) {
    int g = blockIdx.x * 256 + threadIdx.x;
    int row = g >> 6, c = (g & 63) * 8;
    int t = row >> 5, b = row & 31;
    int id = tok[b * 100 + t];
    size_t dst = ((size_t)b * 100 + t) * 2048 + c;
    *(float4*)(cls_in + dst) = *(const float4*)(emb + (size_t)id * 512 + c);
    *(float4*)(cls_in + dst + 4) = *(const float4*)(emb + (size_t)id * 512 + c + 4);
}

// ---------------- MFMA GEMM: C[M,N] = A[M,K]@W[N,K]^T (+bias)(+relu) ----------------
// A, W fp32 row-major; converted to bf16 during LDS staging. 128x128 tile.
__global__ __launch_bounds__(256) void gemm_bt(const float* __restrict__ A, int lda,
                                               const float* __restrict__ W, int ldw,
                                               float* __restrict__ C,
                                               const float* __restrict__ bias0,
                                               const float* __restrict__ bias1,
                                               int N, int K, int relu) {
    __shared__ __align__(16) u16 As[128][40];
    __shared__ __align__(16) u16 Bs[128][40];
    int tid = threadIdx.x;
    int lane = tid & 63, w = tid >> 6;
    int wm = w & 1, wn = w >> 1;
    int l15 = lane & 15, q = lane >> 4;
    f32x4 acc[4][4] = {};
    int sr = tid >> 2, sc = (tid & 3) * 8;
    const float* Ar0 = A + (size_t)(blockIdx.x * 128 + sr) * lda;
    const float* Ar1 = Ar0 + (size_t)64 * lda;
    const float* Wr0 = W + (size_t)(blockIdx.y * 128 + sr) * ldw;
    const float* Wr1 = Wr0 + (size_t)64 * ldw;
    for (int kb = 0; kb < K; kb += 32) {
        *(uint4*)&As[sr][sc] = pack8(*(const float4*)(Ar0 + kb + sc), *(const float4*)(Ar0 + kb + sc + 4));
        *(uint4*)&As[sr + 64][sc] = pack8(*(const float4*)(Ar1 + kb + sc), *(const float4*)(Ar1 + kb + sc + 4));
        *(uint4*)&Bs[sr][sc] = pack8(*(const float4*)(Wr0 + kb + sc), *(const float4*)(Wr0 + kb + sc + 4));
        *(uint4*)&Bs[sr + 64][sc] = pack8(*(const float4*)(Wr1 + kb + sc), *(const float4*)(Wr1 + kb + sc + 4));
        __syncthreads();
        bf16x8 af[4], bfr[4];
        for (int i = 0; i < 4; i++) af[i] = *(const bf16x8*)&As[wm * 64 + i * 16 + l15][q * 8];
        for (int j = 0; j < 4; j++) bfr[j] = *(const bf16x8*)&Bs[wn * 64 + j * 16 + l15][q * 8];
        for (int i = 0; i < 4; i++)
            for (int j = 0; j < 4; j++) acc[i][j] = mfma16(af[i], bfr[j], acc[i][j]);
        __syncthreads();
    }
    for (int j = 0; j < 4; j++) {
        int n = blockIdx.y * 128 + wn * 64 + j * 16 + l15;
        float bv = 0.f;
        if (bias0) bv += bias0[n];
        if (bias1) bv += bias1[n];
        for (int i = 0; i < 4; i++) {
            int mb = blockIdx.x * 128 + wm * 64 + i * 16 + q * 4;
            for (int r = 0; r < 4; r++) {
                float v = acc[i][j][r] + bv;
                if (relu) v = v > 0.f ? v : 0.f;
                C[(size_t)(mb + r) * N + n] = v;
            }
        }
    }
}

// ---------------- encoder step (both dirs), 1 wave/block, grid=128 ----------------
__global__ __launch_bounds__(64) void enc_step(const u16* __restrict__ Whh_f,
                                               const u16* __restrict__ Whh_b,
                                               const float* __restrict__ Pf,
                                               const float* __restrict__ Pb,
                                               const u16* __restrict__ hb_in,   // [dir][32][512] bf16
                                               u16* __restrict__ hb_out,
                                               float* __restrict__ c_enc,       // [dir][32][512] fp32
                                               float* __restrict__ enc_f32,     // [b][s][1024] fp32
                                               int t) {
    int blk = blockIdx.x;
    int dir = blk >> 6;
    int mt = (blk >> 5) & 1, jt = blk & 31;
    int lane = threadIdx.x;
    int l15 = lane & 15, q = lane >> 4;
    const u16* Whh = dir ? Whh_b : Whh_f;
    const float* P = dir ? Pb : Pf;
    int s = dir ? (99 - t) : t;
    const u16* hin = hb_in + dir * 32 * 512;
    f32x4 acc[4] = {};
    const u16* arow = hin + (mt * 16 + l15) * 512 + q * 8;
    for (int kb = 0; kb < 512; kb += 32) {
        bf16x8 a = *(const bf16x8*)(arow + kb);
        for (int g = 0; g < 4; g++) {
            bf16x8 b = *(const bf16x8*)(Whh + (size_t)(g * 512 + jt * 16 + l15) * 512 + kb + q * 8);
            acc[g] = mfma16(a, b, acc[g]);
        }
    }
    int j = jt * 16 + l15;
    for (int r = 0; r < 4; r++) {
        int b_ = mt * 16 + q * 4 + r;
        const float* Pr = P + ((size_t)s * 32 + b_) * 2048;
        float gi = acc[0][r] + Pr[j];
        float gf = acc[1][r] + Pr[512 + j];
        float gg = acc[2][r] + Pr[1024 + j];
        float go = acc[3][r] + Pr[1536 + j];
        float* cp = c_enc + (dir * 32 + b_) * 512 + j;
        float cn = sigm(gf) * (*cp) + sigm(gi) * tanh_(gg);
        float hn = sigm(go) * tanh_(cn);
        *cp = cn;
        hb_out[(dir * 32 + b_) * 512 + j] = f2bf(hn);
        enc_f32[((size_t)b_ * 100 + s) * 1024 + dir * 512 + j] = hn;
    }
}

// decoder init: h/c from final forward-direction encoder state
__global__ __launch_bounds__(256) void init_dec(const u16* __restrict__ h_enc,
                                                const float* __restrict__ c_enc,
                                                u16* __restrict__ xcat0,
                                                float* __restrict__ c_dec) {
    int idx = blockIdx.x * 256 + threadIdx.x;    // 16384 = 32*512
    int b = idx >> 9, j = idx & 511;
    xcat0[b * 1536 + 1024 + j] = h_enc[b * 512 + j];
    c_dec[idx] = c_enc[idx];
}

// pp[32,1536] = h @ a1Wh^T ; 1 wave/block, grid=192
__global__ __launch_bounds__(64) void dpp_step(const u16* __restrict__ xcat_in,
                                               const u16* __restrict__ a1Wh,
                                               float* __restrict__ pp) {
    int blk = blockIdx.x;
    int mt = blk / 96, nt = blk % 96;
    int lane = threadIdx.x, l15 = lane & 15, q = lane >> 4;
    f32x4 acc = {};
    for (int kb = 0; kb < 512; kb += 32) {
        bf16x8 a = *(const bf16x8*)(xcat_in + (mt * 16 + l15) * 1536 + 1024 + kb + q * 8);
        bf16x8 b = *(const bf16x8*)(a1Wh + (size_t)(nt * 16 + l15) * 512 + kb + q * 8);
        acc = mfma16(a, b, acc);
    }
    int n = nt * 16 + l15;
    for (int r = 0; r < 4; r++) pp[(mt * 16 + q * 4 + r) * 1536 + n] = acc[r];
}

// scores[b,s] = att2_b + sum_k a2[k]*relu(encpre[b,s,k] + pp[b,k]) ; wave per (b,s)
__global__ __launch_bounds__(256) void score_step(const float* __restrict__ encpre,
                                                  const float* __restrict__ pp,
                                                  const float* __restrict__ a2W,
                                                  const float* __restrict__ a2b,
                                                  float* __restrict__ scores) {
    int wv = blockIdx.x * 4 + (threadIdx.x >> 6);
    int lane = threadIdx.x & 63;
    int b = wv / 100, s = wv % 100;
    const float* ep = encpre + (size_t)(b * 100 + s) * 1536;
    const float* pb = pp + b * 1536;
    float acc = 0.f;
    for (int i = 0; i < 24; i++) {
        int k = i * 64 + lane;
        float v = ep[k] + pb[k];
        v = fmaxf(v, 0.f);
        acc += v * a2W[k];
    }
    for (int off = 32; off; off >>= 1) acc += __shfl_xor(acc, off);
    if (lane == 0) scores[b * 100 + s] = acc + a2b[0];
}

// softmax over s (per b) + ctx ; block = (b, 256-col chunk), grid=128
__global__ __launch_bounds__(256) void ctx_step(const float* __restrict__ scores,
                                                const float* __restrict__ enc_f32,
                                                u16* __restrict__ xcat_ctx,
                                                float* __restrict__ cls_in, int t) {
    __shared__ float sm[100];
    __shared__ float rmax, rsum;
    int b = blockIdx.x >> 2, kc = (blockIdx.x & 3) * 256;
    int tid = threadIdx.x;
    if (tid < 100) sm[tid] = scores[b * 100 + tid];
    __syncthreads();
    if (tid < 64) {
        float m = -1e30f;
        for (int s = tid; s < 100; s += 64) m = fmaxf(m, sm[s]);
        for (int o = 32; o; o >>= 1) m = fmaxf(m, __shfl_xor(m, o));
        if (tid == 0) rmax = m;
    }
    __syncthreads();
    if (tid < 100) sm[tid] = __expf(sm[tid] - rmax);
    __syncthreads();
    if (tid < 64) {
        float s3 = 0.f;
        for (int s = tid; s < 100; s += 64) s3 += sm[s];
        for (int o = 32; o; o >>= 1) s3 += __shfl_xor(s3, o);
        if (tid == 0) rsum = s3;
    }
    __syncthreads();
    float inv = 1.0f / rsum;
    int k = kc + tid;
    const float* eb = enc_f32 + (size_t)b * 100 * 1024 + k;
    float acc = 0.f;
    for (int s = 0; s < 100; s++) acc += sm[s] * eb[s * 1024];
    acc *= inv;
    xcat_ctx[b * 1536 + k] = f2bf(acc);
    cls_in[((size_t)b * 100 + t) * 2048 + 512 + k] = acc;
}

// decoder LSTM step: gates = xcat @ W2^T + Dpre ; 1 wave/block, grid=64
__global__ __launch_bounds__(64) void dec_step(const u16* __restrict__ xcat_in,
                                               const u16* __restrict__ W2,
                                               const float* __restrict__ Dpre,  // rows b*100+t
                                               float* __restrict__ c_dec,
                                               u16* __restrict__ xcat_next,
                                               float* __restrict__ cls_in, int t) {
    int blk = blockIdx.x;
    int mt = blk >> 5, jt = blk & 31;
    int lane = threadIdx.x, l15 = lane & 15, q = lane >> 4;
    f32x4 acc[4] = {};
    for (int kb = 0; kb < 1536; kb += 32) {
        bf16x8 a = *(const bf16x8*)(xcat_in + (mt * 16 + l15) * 1536 + kb + q * 8);
        for (int g = 0; g < 4; g++) {
            bf16x8 b = *(const bf16x8*)(W2 + (size_t)(g * 512 + jt * 16 + l15) * 1536 + kb + q * 8);
            acc[g] = mfma16(a, b, acc[g]);
        }
    }
    int j = jt * 16 + l15;
    for (int r = 0; r < 4; r++) {
        int b_ = mt * 16 + q * 4 + r;
        const float* Pr = Dpre + ((size_t)b_ * 100 + t) * 2048;
        float gi = acc[0][r] + Pr[j];
        float gf = acc[1][r] + Pr[512 + j];
        float gg = acc[2][r] + Pr[1024 + j];
        float go = acc[3][r] + Pr[1536 + j];
        float* cp = c_dec + b_ * 512 + j;
        float cn = sigm(gf) * (*cp) + sigm(gi) * tanh_(gg);
        float hn = sigm(go) * tanh_(cn);
        *cp = cn;
        xcat_next[b_ * 1536 + 1024 + j] = f2bf(hn);
        cls_in[((size_t)b_ * 100 + t) * 2048 + 1536 + j] = hn;
    }
}

extern "C" void kernel_launch(void* const* d_in, const int* in_sizes, int n_in,
                              void* d_out, int out_size, void* d_ws, size_t ws_size,
                              hipStream_t stream) {
    const int* src_tok = (const int*)d_in[0];
    const int* tgt_tok = (const int*)d_in[1];
    const float* src_emb = (const float*)d_in[2];
    const float* tgt_emb = (const float*)d_in[3];
    const float* eWih_f = (const float*)d_in[4];
    const float* eWhh_f = (const float*)d_in[5];
    const float* ebih_f = (const float*)d_in[6];
    const float* ebhh_f = (const float*)d_in[7];
    const float* eWih_b = (const float*)d_in[8];
    const float* eWhh_b = (const float*)d_in[9];
    const float* ebih_b = (const float*)d_in[10];
    const float* ebhh_b = (const float*)d_in[11];
    const float* dWih = (const float*)d_in[12];
    const float* dWhh = (const float*)d_in[13];
    const float* dbih = (const float*)d_in[14];
    const float* dbhh = (const float*)d_in[15];
    const float* a1W = (const float*)d_in[16];
    const float* a1b = (const float*)d_in[17];
    const float* a2W = (const float*)d_in[18];
    const float* a2b = (const float*)d_in[19];
    const float* c1W = (const float*)d_in[20];
    const float* c1b = (const float*)d_in[21];
    const float* c2W = (const float*)d_in[22];
    const float* c2b = (const float*)d_in[23];
    float* out = (float*)d_out;

    char* W = (char*)d_ws;
    size_t off = 0;
    auto alloc = [&](size_t bytes) { size_t o = off; off = (off + bytes + 255) & ~(size_t)255; return o; };
    size_t o_xs     = alloc((size_t)3200 * 512 * 4);
    size_t o_Pf     = alloc((size_t)3200 * 2048 * 4);
    size_t o_Pb     = alloc((size_t)3200 * 2048 * 4);
    size_t o_Dpre   = alloc((size_t)3200 * 2048 * 4);
    size_t o_ef32   = alloc((size_t)3200 * 1024 * 4);
    size_t o_encpre = alloc((size_t)3200 * 1536 * 4);
    size_t o_clsin  = alloc((size_t)3200 * 2048 * 4);
    size_t o_h1     = alloc((size_t)3200 * 1024 * 4);
    size_t o_W2     = alloc((size_t)2048 * 1536 * 2);
    size_t o_whhf   = alloc((size_t)2048 * 512 * 2);
    size_t o_whhb   = alloc((size_t)2048 * 512 * 2);
    size_t o_a1wh   = alloc((size_t)1536 * 512 * 2);
    size_t o_hb     = alloc((size_t)2 * 2 * 32 * 512 * 2);   // [parity][dir][b][k] bf16
    size_t o_cenc   = alloc((size_t)2 * 32 * 512 * 4);
    size_t o_xcat   = alloc((size_t)2 * 32 * 1536 * 2);      // [parity][b][ctx(1024)|h(512)] bf16
    size_t o_cdec   = alloc((size_t)32 * 512 * 4);
    size_t o_pp     = alloc((size_t)32 * 1536 * 4);
    size_t o_sc     = alloc((size_t)3200 * 4);

    float* xs = (float*)(W + o_xs);
    float* Pf = (float*)(W + o_Pf);
    float* Pb = (float*)(W + o_Pb);
    float* Dpre = (float*)(W + o_Dpre);
    float* ef32 = (float*)(W + o_ef32);
    float* encpre = (float*)(W + o_encpre);
    float* clsin = (float*)(W + o_clsin);
    float* h1 = (float*)(W + o_h1);
    u16* W2 = (u16*)(W + o_W2);
    u16* whhf = (u16*)(W + o_whhf);
    u16* whhb = (u16*)(W + o_whhb);
    u16* a1wh = (u16*)(W + o_a1wh);
    u16* hb = (u16*)(W + o_hb);
    float* cenc = (float*)(W + o_cenc);
    u16* xcat = (u16*)(W + o_xcat);
    float* cdec = (float*)(W + o_cdec);
    float* pp = (float*)(W + o_pp);
    float* sc = (float*)(W + o_sc);

    // zero recurrent state (ws is re-poisoned before every timed launch)
    hipMemsetAsync(hb, 0, (size_t)2 * 32 * 512 * 2, stream);      // parity-0 h, both dirs
    hipMemsetAsync(cenc, 0, (size_t)2 * 32 * 512 * 4, stream);

    // weight prep (fp32 -> bf16)
    convert_f2b<<<1024, 256, 0, stream>>>(eWhh_f, whhf, 2048 * 512);
    convert_f2b<<<1024, 256, 0, stream>>>(eWhh_b, whhb, 2048 * 512);
    build_w2<<<2048, 256, 0, stream>>>(dWih, dWhh, W2);
    build_a1wh<<<1536, 256, 0, stream>>>(a1W, a1wh);

    embed_src<<<800, 256, 0, stream>>>(src_tok, src_emb, xs);
    embed_tgt<<<800, 256, 0, stream>>>(tgt_tok, tgt_emb, clsin);

    // input projections
    gemm_bt<<<dim3(25, 16), 256, 0, stream>>>(xs, 512, eWih_f, 512, Pf, ebih_f, ebhh_f, 2048, 512, 0);
    gemm_bt<<<dim3(25, 16), 256, 0, stream>>>(xs, 512, eWih_b, 512, Pb, ebih_b, ebhh_b, 2048, 512, 0);
    // Dpre rows = b*100+t (A = clsin emb columns)
    gemm_bt<<<dim3(25, 16), 256, 0, stream>>>(clsin, 2048, dWih, 1536, Dpre, dbih, dbhh, 2048, 512, 0);

    // encoder recurrence
    for (int t = 0; t < 100; t++) {
        const u16* hin = hb + ((t & 1) ? 2 * 32 * 512 : 0);
        u16* hout = hb + ((t & 1) ? 0 : 2 * 32 * 512);
        enc_step<<<128, 64, 0, stream>>>(whhf, whhb, Pf, Pb, hin, hout, cenc, ef32, t);
    }

    // attention enc-part: encpre[b*100+s][1536] = enc_out @ a1W[:, :1024]^T + a1b
    gemm_bt<<<dim3(25, 12), 256, 0, stream>>>(ef32, 1024, a1W, 1536, encpre, a1b, nullptr, 1536, 1024, 0);

    init_dec<<<64, 256, 0, stream>>>(hb, cenc, xcat, cdec);

    for (int t = 0; t < 100; t++) {
        u16* xin = xcat + (size_t)(t & 1) * 32 * 1536;
        u16* xnext = xcat + (size_t)((t + 1) & 1) * 32 * 1536;
        dpp_step<<<192, 64, 0, stream>>>(xin, a1wh, pp);
        score_step<<<800, 256, 0, stream>>>(encpre, pp, a2W, a2b, sc);
        ctx_step<<<128, 256, 0, stream>>>(sc, ef32, xin, clsin, t);
        dec_step<<<64, 64, 0, stream>>>(xin, W2, Dpre, cdec, xnext, clsin, t);
    }

    // classifier
    gemm_bt<<<dim3(25, 8), 256, 0, stream>>>(clsin, 2048, c1W, 2048, h1, c1b, nullptr, 1024, 2048, 1);
    gemm_bt<<<dim3(25, 250), 256, 0, stream>>>(h1, 1024, c2W, 1024, out, c2b, nullptr, 32000, 1024, 0);
}